// Round 5
// baseline (921.236 us; speedup 1.0000x reference)
//
#include <hip/hip_runtime.h>
#include <hip/hip_bf16.h>
#include <hip/hip_fp16.h>

typedef _Float16 half8 __attribute__((ext_vector_type(8)));
typedef _Float16 half4 __attribute__((ext_vector_type(4)));
typedef float f32x4 __attribute__((ext_vector_type(4)));

#define S_LEN 2048
#define D_MODEL 1024
#define NH 16
#define HEAD_D 64
#define BATCH 2
#define NGLOB 16
// band half-width = WINDOW/2 = 32 (inclusive)

// ---------------- zero-stream the attn buffer (537 MB) ----------------
__global__ __launch_bounds__(256) void zero_attn_f32(float* __restrict__ p, long n4) {
  const long stride = (long)gridDim.x * 256;
  f32x4 z = {0.f, 0.f, 0.f, 0.f};
  for (long i = (long)blockIdx.x * 256 + threadIdx.x; i < n4; i += stride)
    ((f32x4*)p)[i] = z;
}

// ---------------- fp32 -> fp16 convert (vectorized) ----------------
__global__ __launch_bounds__(256) void cvt_f32_f16(const float* __restrict__ src,
                                                   _Float16* __restrict__ dst, int n) {
  int i = (blockIdx.x * 256 + threadIdx.x) * 4;
  if (i < n) {
    f32x4 v = *(const f32x4*)(src + i);
    half4 h;
    h[0] = (_Float16)v[0]; h[1] = (_Float16)v[1];
    h[2] = (_Float16)v[2]; h[3] = (_Float16)v[3];
    *(half4*)(dst + i) = h;
  }
}

// ---------------- fp16 MFMA GEMM: C[M,N] = A[M,K] @ W[N,K]^T + bias ----------------
// 128x128 tile, BK=32, 4 waves (2x2), each wave 64x64 = 4x4 fragments of 16x16x32.
__device__ __forceinline__ void load_lds16(const void* g, void* l) {
  __builtin_amdgcn_global_load_lds((const __attribute__((address_space(1))) void*)g,
                                   (__attribute__((address_space(3))) void*)l, 16, 0, 0);
}

__global__ __launch_bounds__(256) void gemm_bt_f16(
    const _Float16* __restrict__ A,   // [M,K]
    const _Float16* __restrict__ W,   // [N,K]
    const float*    __restrict__ bias,// [N]
    float*          __restrict__ Cf,  // [M,N] fp32 out (or null)
    _Float16*       __restrict__ Ch,  // [M,N] fp16 out (or null)
    int M, int N, int K)
{
  __shared__ _Float16 sA[128 * 32];
  __shared__ _Float16 sW[128 * 32];
  const int tid = threadIdx.x;
  const int l = tid & 63;
  const int w = tid >> 6;
  const int wr = w >> 1, wc = w & 1;
  const int m0 = blockIdx.y * 128, n0 = blockIdx.x * 128;

  f32x4 acc[4][4] = {};

  for (int k0 = 0; k0 < K; k0 += 32) {
    {
      int c = tid;
      int row = c >> 2, kc = c & 3;
      load_lds16(A + (size_t)(m0 + row) * K + k0 + kc * 8, sA + c * 8);
      load_lds16(W + (size_t)(n0 + row) * K + k0 + kc * 8, sW + c * 8);
      c = tid + 256;
      row = c >> 2; kc = c & 3;
      load_lds16(A + (size_t)(m0 + row) * K + k0 + kc * 8, sA + c * 8);
      load_lds16(W + (size_t)(n0 + row) * K + k0 + kc * 8, sW + c * 8);
    }
    __syncthreads();

    half8 av[4], bv[4];
#pragma unroll
    for (int mi = 0; mi < 4; ++mi)
      av[mi] = *(const half8*)&sA[(wr * 64 + mi * 16 + (l & 15)) * 32 + (l >> 4) * 8];
#pragma unroll
    for (int ni = 0; ni < 4; ++ni)
      bv[ni] = *(const half8*)&sW[(wc * 64 + ni * 16 + (l & 15)) * 32 + (l >> 4) * 8];
#pragma unroll
    for (int mi = 0; mi < 4; ++mi)
#pragma unroll
      for (int ni = 0; ni < 4; ++ni)
        acc[mi][ni] = __builtin_amdgcn_mfma_f32_16x16x32_f16(av[mi], bv[ni], acc[mi][ni], 0, 0, 0);
    __syncthreads();
  }

#pragma unroll
  for (int mi = 0; mi < 4; ++mi) {
#pragma unroll
    for (int ni = 0; ni < 4; ++ni) {
      int row = m0 + wr * 64 + mi * 16 + ((l >> 4) << 2);
      int col = n0 + wc * 64 + ni * 16 + (l & 15);
      float bc = bias[col];
#pragma unroll
      for (int r = 0; r < 4; ++r) {
        float v = acc[mi][ni][r] + bc;
        size_t idx = (size_t)(row + r) * N + col;
        if (Cf) Cf[idx] = v;
        if (Ch) Ch[idx] = (_Float16)v;
      }
    }
  }
}

// ---------------- band-attention: rows i>=16, sparse attn stores ----------------
// grid: B*H*(S/32) blocks of 256 (4 waves); each wave handles 8 rows.
// LDS K/V staged fp32 with stride 65 (bank-conflict-free).
__global__ __launch_bounds__(256) void attn_band(
    const _Float16* __restrict__ Qh, const _Float16* __restrict__ Kh,
    const _Float16* __restrict__ Vh,
    float* __restrict__ attn, _Float16* __restrict__ ctx)
{
  __shared__ float Kb[96 * 65];
  __shared__ float Vb[96 * 65];
  __shared__ float Kg[16 * 65];
  __shared__ float Vg[16 * 65];
  __shared__ float qbuf[4][64];
  __shared__ float pbuf[4][128];

  const int bid = blockIdx.x;
  const int rb = bid & 63;          // 64 row-blocks
  const int h  = (bid >> 6) & 15;
  const int b  = bid >> 10;
  const int i0 = rb * 32;
  const int jb0 = max(i0 - 32, 0);
  const int jb1 = min(i0 + 63, S_LEN - 1);
  const int Wn = jb1 - jb0 + 1;     // <= 96
  const int tid = threadIdx.x;

  // stage band K/V
  for (int s = tid; s < Wn * 16; s += 256) {
    int j = s >> 4, d4 = (s & 15) << 2;
    size_t base = ((size_t)b * S_LEN + jb0 + j) * D_MODEL + h * HEAD_D + d4;
    half4 kv = *(const half4*)(Kh + base);
    half4 vv = *(const half4*)(Vh + base);
    int o = j * 65 + d4;
    Kb[o] = (float)kv[0]; Kb[o+1] = (float)kv[1]; Kb[o+2] = (float)kv[2]; Kb[o+3] = (float)kv[3];
    Vb[o] = (float)vv[0]; Vb[o+1] = (float)vv[1]; Vb[o+2] = (float)vv[2]; Vb[o+3] = (float)vv[3];
  }
  // stage global 16 K/V rows (16*16 = 256 slots exactly)
  {
    int s = tid;
    int j = s >> 4, d4 = (s & 15) << 2;
    size_t base = ((size_t)b * S_LEN + j) * D_MODEL + h * HEAD_D + d4;
    half4 kv = *(const half4*)(Kh + base);
    half4 vv = *(const half4*)(Vh + base);
    int o = j * 65 + d4;
    Kg[o] = (float)kv[0]; Kg[o+1] = (float)kv[1]; Kg[o+2] = (float)kv[2]; Kg[o+3] = (float)kv[3];
    Vg[o] = (float)vv[0]; Vg[o+1] = (float)vv[1]; Vg[o+2] = (float)vv[2]; Vg[o+3] = (float)vv[3];
  }
  __syncthreads();

  const int l = tid & 63, w = tid >> 6;
  for (int rr = 0; rr < 8; ++rr) {
    const int i = i0 + w * 8 + rr;
    if (i < NGLOB) continue;  // handled by attn_global

    qbuf[w][l] = (float)Qh[((size_t)b * S_LEN + i) * D_MODEL + h * HEAD_D + l];

    const int b0n = max(i - 32, 16);
    const int b1n = min(i + 32, S_LEN - 1);
    const int nj = 16 + (b1n - b0n + 1);   // <= 81

    const int  j1 = (l < 16) ? l : (b0n + l - 16);
    const bool v1 = l < nj;
    const int  jj2 = l + 64;
    const bool v2 = jj2 < nj;
    const int  j2 = v2 ? (b0n + jj2 - 16) : b0n;

    const float* kr1 = (l < 16) ? &Kg[l * 65] : &Kb[((v1 ? j1 : b0n) - jb0) * 65];
    const float* kr2 = &Kb[(j2 - jb0) * 65];

    float s1 = 0.f, s2 = 0.f;
#pragma unroll 8
    for (int d = 0; d < 64; ++d) {
      float qd = qbuf[w][d];
      s1 += qd * kr1[d];
      s2 += qd * kr2[d];
    }
    s1 *= 0.125f; s2 *= 0.125f;
    if (!v1) s1 = -1e30f;
    if (!v2) s2 = -1e30f;

    float mx = fmaxf(s1, s2);
#pragma unroll
    for (int o = 32; o; o >>= 1) mx = fmaxf(mx, __shfl_xor(mx, o));
    float e1 = v1 ? __expf(s1 - mx) : 0.f;
    float e2 = v2 ? __expf(s2 - mx) : 0.f;
    float sm = e1 + e2;
#pragma unroll
    for (int o = 32; o; o >>= 1) sm += __shfl_xor(sm, o);
    float inv = 1.f / sm;
    float p1 = e1 * inv, p2 = e2 * inv;

    float* arow = attn + ((size_t)(b * NH + h) * S_LEN + i) * S_LEN;
    if (v1) arow[j1] = p1;
    if (v2) arow[b0n + jj2 - 16] = p2;

    pbuf[w][l] = p1;
    pbuf[w][64 + l] = p2;

    float c = 0.f;
    for (int jj = 0; jj < nj; ++jj) {
      float p = pbuf[w][jj];
      const float* vr = (jj < 16) ? &Vg[jj * 65] : &Vb[(b0n + jj - 16 - jb0) * 65];
      c += p * vr[l];
    }
    ctx[((size_t)b * S_LEN + i) * D_MODEL + h * HEAD_D + l] = (_Float16)c;
  }
}

// ---------------- global rows: i < 16, full 2048-wide softmax ----------------
// grid: B*H*16 blocks of 256
__global__ __launch_bounds__(256) void attn_global(
    const _Float16* __restrict__ Qh, const _Float16* __restrict__ Kh,
    const _Float16* __restrict__ Vh,
    float* __restrict__ attn, _Float16* __restrict__ ctx)
{
  __shared__ float p[S_LEN];
  __shared__ float qbuf[64];
  __shared__ float red[8];
  __shared__ float part[4][64];

  const int bid = blockIdx.x;
  const int i = bid & 15;
  const int h = (bid >> 4) & 15;
  const int b = bid >> 8;
  const int tid = threadIdx.x;

  if (tid < 64) qbuf[tid] = (float)Qh[((size_t)b * S_LEN + i) * D_MODEL + h * HEAD_D + tid];
  __syncthreads();

  float lmax = -1e30f;
  for (int j = tid; j < S_LEN; j += 256) {
    const half8* kr = (const half8*)(Kh + ((size_t)b * S_LEN + j) * D_MODEL + h * HEAD_D);
    float s = 0.f;
#pragma unroll
    for (int c8 = 0; c8 < 8; ++c8) {
      half8 kv = kr[c8];
#pragma unroll
      for (int r = 0; r < 8; ++r) s += qbuf[c8 * 8 + r] * (float)kv[r];
    }
    s *= 0.125f;
    p[j] = s;
    lmax = fmaxf(lmax, s);
  }
#pragma unroll
  for (int o = 32; o; o >>= 1) lmax = fmaxf(lmax, __shfl_xor(lmax, o));
  if ((tid & 63) == 0) red[tid >> 6] = lmax;
  __syncthreads();
  const float mx = fmaxf(fmaxf(red[0], red[1]), fmaxf(red[2], red[3]));

  float lsum = 0.f;
  for (int j = tid; j < S_LEN; j += 256) {
    float e = __expf(p[j] - mx);
    p[j] = e;
    lsum += e;
  }
#pragma unroll
  for (int o = 32; o; o >>= 1) lsum += __shfl_xor(lsum, o);
  if ((tid & 63) == 0) red[4 + (tid >> 6)] = lsum;
  __syncthreads();
  const float inv = 1.f / (red[4] + red[5] + red[6] + red[7]);

  float* arow = attn + ((size_t)(b * NH + h) * S_LEN + i) * S_LEN;
  for (int j = tid; j < S_LEN; j += 256) {
    float pv = p[j] * inv;
    p[j] = pv;
    arow[j] = pv;
  }
  __syncthreads();

  const int d = tid & 63, c4 = tid >> 6;
  float c = 0.f;
  for (int j = c4 * 512; j < c4 * 512 + 512; ++j)
    c += p[j] * (float)Vh[((size_t)b * S_LEN + j) * D_MODEL + h * HEAD_D + d];
  part[c4][d] = c;
  __syncthreads();
  if (tid < 64) {
    float cc = part[0][tid] + part[1][tid] + part[2][tid] + part[3][tid];
    ctx[((size_t)b * S_LEN + i) * D_MODEL + h * HEAD_D + tid] = (_Float16)cc;
  }
}

// ---------------- launch ----------------
extern "C" void kernel_launch(void* const* d_in, const int* in_sizes, int n_in,
                              void* d_out, int out_size, void* d_ws, size_t ws_size,
                              hipStream_t stream) {
  const float* query = (const float*)d_in[0];
  const float* key   = (const float*)d_in[1];
  const float* value = (const float*)d_in[2];
  const float* Wq = (const float*)d_in[3];
  const float* bq = (const float*)d_in[4];
  const float* Wk = (const float*)d_in[5];
  const float* bk = (const float*)d_in[6];
  const float* Wv = (const float*)d_in[7];
  const float* bv = (const float*)d_in[8];
  const float* Wo = (const float*)d_in[9];
  const float* bo = (const float*)d_in[10];

  float* out  = (float*)d_out;
  float* attn = out + (size_t)BATCH * S_LEN * D_MODEL;

  const size_t XN = (size_t)BATCH * S_LEN * D_MODEL;  // 4,194,304
  const size_t WN = (size_t)D_MODEL * D_MODEL;        // 1,048,576
  _Float16* ws   = (_Float16*)d_ws;
  _Float16* X16  = ws;          // reused for query/key/value in turn
  _Float16* W16q = ws + XN;
  _Float16* W16k = W16q + WN;
  _Float16* W16v = W16k + WN;
  _Float16* W16o = W16v + WN;
  _Float16* Q16  = W16o + WN;
  _Float16* K16  = Q16 + XN;
  _Float16* V16  = K16 + XN;
  _Float16* C16  = V16 + XN;
  // total: 5*XN + 4*WN = 25,165,824 halfs = 48 MiB of ws

  const int M = BATCH * S_LEN;  // 4096

  // 1. zero the attn matrix with a streaming kernel (rocclr fill has 4x write
  //    amplification; a grid-stride f32x4 store streams at ~6 TB/s)
  const long ATTN_N4 = (long)BATCH * NH * S_LEN * S_LEN / 4;  // 33,554,432 f32x4
  zero_attn_f32<<<4096, 256, 0, stream>>>(attn, ATTN_N4);

  // weights -> fp16
  cvt_f32_f16<<<WN / 1024, 256, 0, stream>>>(Wq, W16q, (int)WN);
  cvt_f32_f16<<<WN / 1024, 256, 0, stream>>>(Wk, W16k, (int)WN);
  cvt_f32_f16<<<WN / 1024, 256, 0, stream>>>(Wv, W16v, (int)WN);
  cvt_f32_f16<<<WN / 1024, 256, 0, stream>>>(Wo, W16o, (int)WN);

  dim3 gg(D_MODEL / 128, M / 128);  // 8 x 32

  // Q = query @ Wq^T + bq
  cvt_f32_f16<<<XN / 1024, 256, 0, stream>>>(query, X16, (int)XN);
  gemm_bt_f16<<<gg, 256, 0, stream>>>(X16, W16q, bq, nullptr, Q16, M, D_MODEL, D_MODEL);
  // K
  cvt_f32_f16<<<XN / 1024, 256, 0, stream>>>(key, X16, (int)XN);
  gemm_bt_f16<<<gg, 256, 0, stream>>>(X16, W16k, bk, nullptr, K16, M, D_MODEL, D_MODEL);
  // V
  cvt_f32_f16<<<XN / 1024, 256, 0, stream>>>(value, X16, (int)XN);
  gemm_bt_f16<<<gg, 256, 0, stream>>>(X16, W16v, bv, nullptr, V16, M, D_MODEL, D_MODEL);

  // attention (band rows sparse-store into zeroed attn; global rows full)
  attn_band<<<BATCH * NH * (S_LEN / 32), 256, 0, stream>>>(Q16, K16, V16, attn, C16);
  attn_global<<<BATCH * NH * NGLOB, 256, 0, stream>>>(Q16, K16, V16, attn, C16);

  // out = ctx @ Wo^T + bo
  gemm_bt_f16<<<gg, 256, 0, stream>>>(C16, W16o, bo, out, nullptr, M, D_MODEL, D_MODEL);
}

// Round 8
// 789.450 us; speedup vs baseline: 1.1669x; 1.1669x over previous
//
#include <hip/hip_runtime.h>
#include <hip/hip_bf16.h>
#include <hip/hip_fp16.h>

typedef _Float16 half8 __attribute__((ext_vector_type(8)));
typedef _Float16 half4 __attribute__((ext_vector_type(4)));
typedef float f32x4 __attribute__((ext_vector_type(4)));

#define S_LEN 2048
#define D_MODEL 1024
#define NH 16
#define HEAD_D 64
#define BATCH 2
#define NGLOB 16
// band half-width = WINDOW/2 = 32 (inclusive)

// ---------------- fp32 -> fp16 converts, batched ----------------
__global__ __launch_bounds__(256) void cvt_in3(
    const float* __restrict__ s0, const float* __restrict__ s1, const float* __restrict__ s2,
    _Float16* __restrict__ d0, _Float16* __restrict__ d1, _Float16* __restrict__ d2, int n) {
  const float* s = (blockIdx.y == 0) ? s0 : (blockIdx.y == 1) ? s1 : s2;
  _Float16*   d = (blockIdx.y == 0) ? d0 : (blockIdx.y == 1) ? d1 : d2;
  int i = (blockIdx.x * 256 + threadIdx.x) * 4;
  if (i < n) {
    f32x4 v = *(const f32x4*)(s + i);
    half4 h;
    h[0] = (_Float16)v[0]; h[1] = (_Float16)v[1];
    h[2] = (_Float16)v[2]; h[3] = (_Float16)v[3];
    *(half4*)(d + i) = h;
  }
}

__global__ __launch_bounds__(256) void cvt_w4(
    const float* __restrict__ s0, const float* __restrict__ s1,
    const float* __restrict__ s2, const float* __restrict__ s3,
    _Float16* __restrict__ d0, _Float16* __restrict__ d1,
    _Float16* __restrict__ d2, _Float16* __restrict__ d3, int n) {
  const float* s = (blockIdx.y == 0) ? s0 : (blockIdx.y == 1) ? s1 : (blockIdx.y == 2) ? s2 : s3;
  _Float16*   d = (blockIdx.y == 0) ? d0 : (blockIdx.y == 1) ? d1 : (blockIdx.y == 2) ? d2 : d3;
  int i = (blockIdx.x * 256 + threadIdx.x) * 4;
  if (i < n) {
    f32x4 v = *(const f32x4*)(s + i);
    half4 h;
    h[0] = (_Float16)v[0]; h[1] = (_Float16)v[1];
    h[2] = (_Float16)v[2]; h[3] = (_Float16)v[3];
    *(half4*)(d + i) = h;
  }
}

// ---------------- fp16 MFMA GEMM helpers ----------------
__device__ __forceinline__ void load_lds16(const void* g, void* l) {
  __builtin_amdgcn_global_load_lds((const __attribute__((address_space(1))) void*)g,
                                   (__attribute__((address_space(3))) void*)l, 16, 0, 0);
}

// Batched QKV projection: z selects (A,W,bias,C). 128x128 tile, BK=32, 4 waves.
// grid (N/128, M/128, 3) = 768 blocks = 3/CU.
__global__ __launch_bounds__(256) void gemm_qkv_f16(
    const _Float16* __restrict__ A0, const _Float16* __restrict__ A1, const _Float16* __restrict__ A2,
    const _Float16* __restrict__ W0, const _Float16* __restrict__ W1, const _Float16* __restrict__ W2,
    const float* __restrict__ b0, const float* __restrict__ b1, const float* __restrict__ b2,
    _Float16* __restrict__ C0, _Float16* __restrict__ C1, _Float16* __restrict__ C2,
    int M, int N, int K)
{
  const int z = blockIdx.z;
  const _Float16* A = (z == 0) ? A0 : (z == 1) ? A1 : A2;
  const _Float16* W = (z == 0) ? W0 : (z == 1) ? W1 : W2;
  const float* bias = (z == 0) ? b0 : (z == 1) ? b1 : b2;
  _Float16* Ch      = (z == 0) ? C0 : (z == 1) ? C1 : C2;

  __shared__ _Float16 sA[128 * 32];
  __shared__ _Float16 sW[128 * 32];
  const int tid = threadIdx.x;
  const int l = tid & 63;
  const int w = tid >> 6;
  const int wr = w >> 1, wc = w & 1;
  const int m0 = blockIdx.y * 128, n0 = blockIdx.x * 128;

  f32x4 acc[4][4] = {};

  for (int k0 = 0; k0 < K; k0 += 32) {
    {
      int c = tid;
      int row = c >> 2, kc = c & 3;
      load_lds16(A + (size_t)(m0 + row) * K + k0 + kc * 8, sA + c * 8);
      load_lds16(W + (size_t)(n0 + row) * K + k0 + kc * 8, sW + c * 8);
      c = tid + 256;
      row = c >> 2; kc = c & 3;
      load_lds16(A + (size_t)(m0 + row) * K + k0 + kc * 8, sA + c * 8);
      load_lds16(W + (size_t)(n0 + row) * K + k0 + kc * 8, sW + c * 8);
    }
    __syncthreads();

    half8 av[4], bv[4];
#pragma unroll
    for (int mi = 0; mi < 4; ++mi)
      av[mi] = *(const half8*)&sA[(wr * 64 + mi * 16 + (l & 15)) * 32 + (l >> 4) * 8];
#pragma unroll
    for (int ni = 0; ni < 4; ++ni)
      bv[ni] = *(const half8*)&sW[(wc * 64 + ni * 16 + (l & 15)) * 32 + (l >> 4) * 8];
#pragma unroll
    for (int mi = 0; mi < 4; ++mi)
#pragma unroll
      for (int ni = 0; ni < 4; ++ni)
        acc[mi][ni] = __builtin_amdgcn_mfma_f32_16x16x32_f16(av[mi], bv[ni], acc[mi][ni], 0, 0, 0);
    __syncthreads();
  }

#pragma unroll
  for (int mi = 0; mi < 4; ++mi) {
#pragma unroll
    for (int ni = 0; ni < 4; ++ni) {
      int row = m0 + wr * 64 + mi * 16 + ((l >> 4) << 2);
      int col = n0 + wc * 64 + ni * 16 + (l & 15);
      float bc = bias[col];
#pragma unroll
      for (int r = 0; r < 4; ++r) {
        float v = acc[mi][ni][r] + bc;
        Ch[(size_t)(row + r) * N + col] = (_Float16)v;
      }
    }
  }
}

// Output GEMM: 128x64 tile -> grid (N/64, M/128) = 512 blocks = 2/CU. fp32 out.
__global__ __launch_bounds__(256) void gemm_bt64_f16(
    const _Float16* __restrict__ A,   // [M,K]
    const _Float16* __restrict__ W,   // [N,K]
    const float*    __restrict__ bias,// [N]
    float*          __restrict__ Cf,  // [M,N]
    int M, int N, int K)
{
  __shared__ _Float16 sA[128 * 32];
  __shared__ _Float16 sW[64 * 32];
  const int tid = threadIdx.x;
  const int l = tid & 63;
  const int w = tid >> 6;
  const int wr = w >> 1, wc = w & 1;
  const int m0 = blockIdx.y * 128, n0 = blockIdx.x * 64;

  f32x4 acc[4][2] = {};

  for (int k0 = 0; k0 < K; k0 += 32) {
    {
      int c = tid;
      int row = c >> 2, kc = c & 3;
      load_lds16(A + (size_t)(m0 + row) * K + k0 + kc * 8, sA + c * 8);
      load_lds16(W + (size_t)(n0 + row) * K + k0 + kc * 8, sW + c * 8);  // 64 rows x 4 chunks = 256
      c = tid + 256;
      row = c >> 2; kc = c & 3;
      load_lds16(A + (size_t)(m0 + row) * K + k0 + kc * 8, sA + c * 8);
    }
    __syncthreads();

    half8 av[4], bv[2];
#pragma unroll
    for (int mi = 0; mi < 4; ++mi)
      av[mi] = *(const half8*)&sA[(wr * 64 + mi * 16 + (l & 15)) * 32 + (l >> 4) * 8];
#pragma unroll
    for (int ni = 0; ni < 2; ++ni)
      bv[ni] = *(const half8*)&sW[(wc * 32 + ni * 16 + (l & 15)) * 32 + (l >> 4) * 8];
#pragma unroll
    for (int mi = 0; mi < 4; ++mi)
#pragma unroll
      for (int ni = 0; ni < 2; ++ni)
        acc[mi][ni] = __builtin_amdgcn_mfma_f32_16x16x32_f16(av[mi], bv[ni], acc[mi][ni], 0, 0, 0);
    __syncthreads();
  }

#pragma unroll
  for (int mi = 0; mi < 4; ++mi) {
#pragma unroll
    for (int ni = 0; ni < 2; ++ni) {
      int row = m0 + wr * 64 + mi * 16 + ((l >> 4) << 2);
      int col = n0 + wc * 32 + ni * 16 + (l & 15);
      float bc = bias[col];
#pragma unroll
      for (int r = 0; r < 4; ++r)
        Cf[(size_t)(row + r) * N + col] = acc[mi][ni][r] + bc;
    }
  }
}

// ---------------- band-attention: rows i>=16, full-row attn writes ----------------
// grid: B*H*(S/32) blocks of 256 (4 waves); each wave handles 8 rows.
__global__ __launch_bounds__(256) void attn_band(
    const _Float16* __restrict__ Qh, const _Float16* __restrict__ Kh,
    const _Float16* __restrict__ Vh,
    float* __restrict__ attn, _Float16* __restrict__ ctx)
{
  __shared__ float Kb[96 * 65];
  __shared__ float Vb[96 * 65];
  __shared__ float Kg[16 * 65];
  __shared__ float Vg[16 * 65];
  __shared__ float qbuf[4][64];
  __shared__ float pbuf[4][128];

  const int bid = blockIdx.x;
  const int rb = bid & 63;
  const int h  = (bid >> 6) & 15;
  const int b  = bid >> 10;
  const int i0 = rb * 32;
  const int jb0 = max(i0 - 32, 0);
  const int jb1 = min(i0 + 63, S_LEN - 1);
  const int Wn = jb1 - jb0 + 1;     // <= 96
  const int tid = threadIdx.x;

  for (int s = tid; s < Wn * 16; s += 256) {
    int j = s >> 4, d4 = (s & 15) << 2;
    size_t base = ((size_t)b * S_LEN + jb0 + j) * D_MODEL + h * HEAD_D + d4;
    half4 kv = *(const half4*)(Kh + base);
    half4 vv = *(const half4*)(Vh + base);
    int o = j * 65 + d4;
    Kb[o] = (float)kv[0]; Kb[o+1] = (float)kv[1]; Kb[o+2] = (float)kv[2]; Kb[o+3] = (float)kv[3];
    Vb[o] = (float)vv[0]; Vb[o+1] = (float)vv[1]; Vb[o+2] = (float)vv[2]; Vb[o+3] = (float)vv[3];
  }
  {
    int s = tid;  // 16*16 = 256 slots exactly
    int j = s >> 4, d4 = (s & 15) << 2;
    size_t base = ((size_t)b * S_LEN + j) * D_MODEL + h * HEAD_D + d4;
    half4 kv = *(const half4*)(Kh + base);
    half4 vv = *(const half4*)(Vh + base);
    int o = j * 65 + d4;
    Kg[o] = (float)kv[0]; Kg[o+1] = (float)kv[1]; Kg[o+2] = (float)kv[2]; Kg[o+3] = (float)kv[3];
    Vg[o] = (float)vv[0]; Vg[o+1] = (float)vv[1]; Vg[o+2] = (float)vv[2]; Vg[o+3] = (float)vv[3];
  }
  __syncthreads();

  const int l = tid & 63, w = tid >> 6;
  for (int rr = 0; rr < 8; ++rr) {
    const int i = i0 + w * 8 + rr;
    if (i < NGLOB) continue;  // handled fully by attn_global

    qbuf[w][l] = (float)Qh[((size_t)b * S_LEN + i) * D_MODEL + h * HEAD_D + l];

    const int b0n = max(i - 32, 16);
    const int b1n = min(i + 32, S_LEN - 1);
    const int nj = 16 + (b1n - b0n + 1);   // <= 81

    const int  j1 = (l < 16) ? l : (b0n + l - 16);
    const bool v1 = l < nj;
    const int  jj2 = l + 64;
    const bool v2 = jj2 < nj;
    const int  j2 = v2 ? (b0n + jj2 - 16) : b0n;

    const float* kr1 = (l < 16) ? &Kg[l * 65] : &Kb[((v1 ? j1 : b0n) - jb0) * 65];
    const float* kr2 = &Kb[(j2 - jb0) * 65];

    float s1 = 0.f, s2 = 0.f;
#pragma unroll 8
    for (int d = 0; d < 64; ++d) {
      float qd = qbuf[w][d];
      s1 += qd * kr1[d];
      s2 += qd * kr2[d];
    }
    s1 *= 0.125f; s2 *= 0.125f;
    if (!v1) s1 = -1e30f;
    if (!v2) s2 = -1e30f;

    float mx = fmaxf(s1, s2);
#pragma unroll
    for (int o = 32; o; o >>= 1) mx = fmaxf(mx, __shfl_xor(mx, o));
    float e1 = v1 ? __expf(s1 - mx) : 0.f;
    float e2 = v2 ? __expf(s2 - mx) : 0.f;
    float sm = e1 + e2;
#pragma unroll
    for (int o = 32; o; o >>= 1) sm += __shfl_xor(sm, o);
    float inv = 1.f / sm;
    float p1 = e1 * inv, p2 = e2 * inv;

    pbuf[w][l] = p1;        // pbuf[jj]: jj<16 -> global col jj; else col b0n+jj-16
    pbuf[w][64 + l] = p2;

    // full-row attn write: 2048 floats = 8 x (64 lanes x float4), single pass
    float* arow = attn + ((size_t)(b * NH + h) * S_LEN + i) * S_LEN;
#pragma unroll
    for (int t = 0; t < 8; ++t) {
      const int lo = t * 256;
      const int j0 = lo + l * 4;
      f32x4 o4 = {0.f, 0.f, 0.f, 0.f};
      const bool hasAny = (lo < NGLOB) || !((b1n < lo) || (b0n >= lo + 256));
      if (hasAny) {
#pragma unroll
        for (int r = 0; r < 4; ++r) {
          int j = j0 + r;
          float v = 0.f;
          if (j < NGLOB) v = pbuf[w][j];
          else if (j >= b0n && j <= b1n) v = pbuf[w][16 + j - b0n];
          o4[r] = v;
        }
      }
      *(f32x4*)(arow + j0) = o4;
    }

    float c = 0.f;
    for (int jj = 0; jj < nj; ++jj) {
      float p = pbuf[w][jj];
      const float* vr = (jj < 16) ? &Vg[jj * 65] : &Vb[(b0n + jj - 16 - jb0) * 65];
      c += p * vr[l];
    }
    ctx[((size_t)b * S_LEN + i) * D_MODEL + h * HEAD_D + l] = (_Float16)c;
  }
}

// ---------------- global rows: i < 16, full 2048-wide softmax ----------------
__global__ __launch_bounds__(256) void attn_global(
    const _Float16* __restrict__ Qh, const _Float16* __restrict__ Kh,
    const _Float16* __restrict__ Vh,
    float* __restrict__ attn, _Float16* __restrict__ ctx)
{
  __shared__ float p[S_LEN];
  __shared__ float qbuf[64];
  __shared__ float red[8];
  __shared__ float part[4][64];

  const int bid = blockIdx.x;
  const int i = bid & 15;
  const int h = (bid >> 4) & 15;
  const int b = bid >> 8;
  const int tid = threadIdx.x;

  if (tid < 64) qbuf[tid] = (float)Qh[((size_t)b * S_LEN + i) * D_MODEL + h * HEAD_D + tid];
  __syncthreads();

  float lmax = -1e30f;
  for (int j = tid; j < S_LEN; j += 256) {
    const half8* kr = (const half8*)(Kh + ((size_t)b * S_LEN + j) * D_MODEL + h * HEAD_D);
    float s = 0.f;
#pragma unroll
    for (int c8 = 0; c8 < 8; ++c8) {
      half8 kv = kr[c8];
#pragma unroll
      for (int r = 0; r < 8; ++r) s += qbuf[c8 * 8 + r] * (float)kv[r];
    }
    s *= 0.125f;
    p[j] = s;
    lmax = fmaxf(lmax, s);
  }
#pragma unroll
  for (int o = 32; o; o >>= 1) lmax = fmaxf(lmax, __shfl_xor(lmax, o));
  if ((tid & 63) == 0) red[tid >> 6] = lmax;
  __syncthreads();
  const float mx = fmaxf(fmaxf(red[0], red[1]), fmaxf(red[2], red[3]));

  float lsum = 0.f;
  for (int j = tid; j < S_LEN; j += 256) {
    float e = __expf(p[j] - mx);
    p[j] = e;
    lsum += e;
  }
#pragma unroll
  for (int o = 32; o; o >>= 1) lsum += __shfl_xor(lsum, o);
  if ((tid & 63) == 0) red[4 + (tid >> 6)] = lsum;
  __syncthreads();
  const float inv = 1.f / (red[4] + red[5] + red[6] + red[7]);

  float* arow = attn + ((size_t)(b * NH + h) * S_LEN + i) * S_LEN;
  for (int j = tid; j < S_LEN; j += 256) {
    float pv = p[j] * inv;
    p[j] = pv;
    arow[j] = pv;
  }
  __syncthreads();

  const int d = tid & 63, c4 = tid >> 6;
  float c = 0.f;
  for (int j = c4 * 512; j < c4 * 512 + 512; ++j)
    c += p[j] * (float)Vh[((size_t)b * S_LEN + j) * D_MODEL + h * HEAD_D + d];
  part[c4][d] = c;
  __syncthreads();
  if (tid < 64) {
    float cc = part[0][tid] + part[1][tid] + part[2][tid] + part[3][tid];
    ctx[((size_t)b * S_LEN + i) * D_MODEL + h * HEAD_D + tid] = (_Float16)cc;
  }
}

// ---------------- launch ----------------
extern "C" void kernel_launch(void* const* d_in, const int* in_sizes, int n_in,
                              void* d_out, int out_size, void* d_ws, size_t ws_size,
                              hipStream_t stream) {
  const float* query = (const float*)d_in[0];
  const float* key   = (const float*)d_in[1];
  const float* value = (const float*)d_in[2];
  const float* Wq = (const float*)d_in[3];
  const float* bq = (const float*)d_in[4];
  const float* Wk = (const float*)d_in[5];
  const float* bk = (const float*)d_in[6];
  const float* Wv = (const float*)d_in[7];
  const float* bv = (const float*)d_in[8];
  const float* Wo = (const float*)d_in[9];
  const float* bo = (const float*)d_in[10];

  float* out  = (float*)d_out;
  float* attn = out + (size_t)BATCH * S_LEN * D_MODEL;

  const size_t XN = (size_t)BATCH * S_LEN * D_MODEL;  // 4,194,304
  const size_t WN = (size_t)D_MODEL * D_MODEL;        // 1,048,576
  _Float16* ws   = (_Float16*)d_ws;
  _Float16* X16q = ws;
  _Float16* X16k = X16q + XN;
  _Float16* X16v = X16k + XN;
  _Float16* W16q = X16v + XN;
  _Float16* W16k = W16q + WN;
  _Float16* W16v = W16k + WN;
  _Float16* W16o = W16v + WN;
  _Float16* Q16  = W16o + WN;
  _Float16* K16  = Q16 + XN;
  _Float16* V16  = K16 + XN;
  _Float16* C16  = V16 + XN;
  // total: 7*XN + 4*WN = 33,554,432 halfs = 64 MiB of ws

  const int M = BATCH * S_LEN;  // 4096

  // 1. batched converts (2 dispatches)
  dim3 gi(XN / 1024, 3);
  cvt_in3<<<gi, 256, 0, stream>>>(query, key, value, X16q, X16k, X16v, (int)XN);
  dim3 gw(WN / 1024, 4);
  cvt_w4<<<gw, 256, 0, stream>>>(Wq, Wk, Wv, Wo, W16q, W16k, W16v, W16o, (int)WN);

  // 2. batched Q/K/V projections: one dispatch, 768 blocks = 3/CU
  dim3 gp(D_MODEL / 128, M / 128, 3);  // 8 x 32 x 3
  gemm_qkv_f16<<<gp, 256, 0, stream>>>(X16q, X16k, X16v, W16q, W16k, W16v,
                                       bq, bk, bv, Q16, K16, V16, M, D_MODEL, D_MODEL);

  // 3. attention (attn matrix fully written here: band rows 16.., global rows 0..15)
  attn_band<<<BATCH * NH * (S_LEN / 32), 256, 0, stream>>>(Q16, K16, V16, attn, C16);
  attn_global<<<BATCH * NH * NGLOB, 256, 0, stream>>>(Q16, K16, V16, attn, C16);

  // 4. out = ctx @ Wo^T + bo  (128x64 tile -> 512 blocks = 2/CU)
  dim3 gf(D_MODEL / 64, M / 128);      // 16 x 32
  gemm_bt64_f16<<<gf, 256, 0, stream>>>(C16, W16o, bo, out, M, D_MODEL, D_MODEL);
}

// Round 9
// 782.541 us; speedup vs baseline: 1.1772x; 1.0088x over previous
//
#include <hip/hip_runtime.h>
#include <hip/hip_bf16.h>
#include <hip/hip_fp16.h>

typedef _Float16 half8 __attribute__((ext_vector_type(8)));
typedef _Float16 half4 __attribute__((ext_vector_type(4)));
typedef float f32x4 __attribute__((ext_vector_type(4)));

#define S_LEN 2048
#define D_MODEL 1024
#define NH 16
#define HEAD_D 64
#define BATCH 2
#define NGLOB 16
// band half-width = WINDOW/2 = 32 (inclusive)

// ---------------- fp32 -> fp16 converts, batched ----------------
__global__ __launch_bounds__(256) void cvt_in3(
    const float* __restrict__ s0, const float* __restrict__ s1, const float* __restrict__ s2,
    _Float16* __restrict__ d0, _Float16* __restrict__ d1, _Float16* __restrict__ d2, int n) {
  const float* s = (blockIdx.y == 0) ? s0 : (blockIdx.y == 1) ? s1 : s2;
  _Float16*   d = (blockIdx.y == 0) ? d0 : (blockIdx.y == 1) ? d1 : d2;
  int i = (blockIdx.x * 256 + threadIdx.x) * 4;
  if (i < n) {
    f32x4 v = *(const f32x4*)(s + i);
    half4 h;
    h[0] = (_Float16)v[0]; h[1] = (_Float16)v[1];
    h[2] = (_Float16)v[2]; h[3] = (_Float16)v[3];
    *(half4*)(d + i) = h;
  }
}

__global__ __launch_bounds__(256) void cvt_w4(
    const float* __restrict__ s0, const float* __restrict__ s1,
    const float* __restrict__ s2, const float* __restrict__ s3,
    _Float16* __restrict__ d0, _Float16* __restrict__ d1,
    _Float16* __restrict__ d2, _Float16* __restrict__ d3, int n) {
  const float* s = (blockIdx.y == 0) ? s0 : (blockIdx.y == 1) ? s1 : (blockIdx.y == 2) ? s2 : s3;
  _Float16*   d = (blockIdx.y == 0) ? d0 : (blockIdx.y == 1) ? d1 : (blockIdx.y == 2) ? d2 : d3;
  int i = (blockIdx.x * 256 + threadIdx.x) * 4;
  if (i < n) {
    f32x4 v = *(const f32x4*)(s + i);
    half4 h;
    h[0] = (_Float16)v[0]; h[1] = (_Float16)v[1];
    h[2] = (_Float16)v[2]; h[3] = (_Float16)v[3];
    *(half4*)(d + i) = h;
  }
}

// ---------------- fp16 MFMA GEMM helpers ----------------
__device__ __forceinline__ void load_lds16(const void* g, void* l) {
  __builtin_amdgcn_global_load_lds((const __attribute__((address_space(1))) void*)g,
                                   (__attribute__((address_space(3))) void*)l, 16, 0, 0);
}

// Batched QKV projection, 2-phase double-buffered (T3 minimal recipe):
// issue next-tile global_load_lds BEFORE ds_read+MFMA of current tile; the
// single vmcnt(0)+barrier (inside __syncthreads) lands AFTER the MFMA cluster,
// so loads overlap compute instead of draining at the top of each K-step.
// grid (N/128, M/128, 3) = 768 blocks = 3/CU.
#define STAGE_QKV(buf, k0) do {                                             \
    int c_ = tid;                                                           \
    int row_ = c_ >> 2, kc_ = c_ & 3;                                       \
    load_lds16(A + (size_t)(m0 + row_) * K + (k0) + kc_ * 8, &sA[buf][c_ * 8]); \
    load_lds16(W + (size_t)(n0 + row_) * K + (k0) + kc_ * 8, &sW[buf][c_ * 8]); \
    c_ = tid + 256; row_ = c_ >> 2; kc_ = c_ & 3;                           \
    load_lds16(A + (size_t)(m0 + row_) * K + (k0) + kc_ * 8, &sA[buf][c_ * 8]); \
    load_lds16(W + (size_t)(n0 + row_) * K + (k0) + kc_ * 8, &sW[buf][c_ * 8]); \
  } while (0)

__global__ __launch_bounds__(256) void gemm_qkv_f16(
    const _Float16* __restrict__ A0, const _Float16* __restrict__ A1, const _Float16* __restrict__ A2,
    const _Float16* __restrict__ W0, const _Float16* __restrict__ W1, const _Float16* __restrict__ W2,
    const float* __restrict__ b0, const float* __restrict__ b1, const float* __restrict__ b2,
    _Float16* __restrict__ C0, _Float16* __restrict__ C1, _Float16* __restrict__ C2,
    int M, int N, int K)
{
  const int z = blockIdx.z;
  const _Float16* A = (z == 0) ? A0 : (z == 1) ? A1 : A2;
  const _Float16* W = (z == 0) ? W0 : (z == 1) ? W1 : W2;
  const float* bias = (z == 0) ? b0 : (z == 1) ? b1 : b2;
  _Float16* Ch      = (z == 0) ? C0 : (z == 1) ? C1 : C2;

  __shared__ _Float16 sA[2][128 * 32];
  __shared__ _Float16 sW[2][128 * 32];
  const int tid = threadIdx.x;
  const int l = tid & 63;
  const int w = tid >> 6;
  const int wr = w >> 1, wc = w & 1;
  const int m0 = blockIdx.y * 128, n0 = blockIdx.x * 128;

  f32x4 acc[4][4] = {};

  STAGE_QKV(0, 0);
  __syncthreads();

  int cur = 0;
  for (int k0 = 0; k0 < K; k0 += 32) {
    if (k0 + 32 < K) STAGE_QKV(cur ^ 1, k0 + 32);  // async into other buffer

    half8 av[4], bv[4];
#pragma unroll
    for (int mi = 0; mi < 4; ++mi)
      av[mi] = *(const half8*)&sA[cur][(wr * 64 + mi * 16 + (l & 15)) * 32 + (l >> 4) * 8];
#pragma unroll
    for (int ni = 0; ni < 4; ++ni)
      bv[ni] = *(const half8*)&sW[cur][(wc * 64 + ni * 16 + (l & 15)) * 32 + (l >> 4) * 8];
#pragma unroll
    for (int mi = 0; mi < 4; ++mi)
#pragma unroll
      for (int ni = 0; ni < 4; ++ni)
        acc[mi][ni] = __builtin_amdgcn_mfma_f32_16x16x32_f16(av[mi], bv[ni], acc[mi][ni], 0, 0, 0);

    __syncthreads();   // vmcnt(0)+lgkmcnt(0)+barrier: next tile staged, cur fully read
    cur ^= 1;
  }

#pragma unroll
  for (int mi = 0; mi < 4; ++mi) {
#pragma unroll
    for (int ni = 0; ni < 4; ++ni) {
      int row = m0 + wr * 64 + mi * 16 + ((l >> 4) << 2);
      int col = n0 + wc * 64 + ni * 16 + (l & 15);
      float bc = bias[col];
#pragma unroll
      for (int r = 0; r < 4; ++r) {
        float v = acc[mi][ni][r] + bc;
        Ch[(size_t)(row + r) * N + col] = (_Float16)v;
      }
    }
  }
}

// Output GEMM: 128x64 tile, 2-phase double-buffered. grid (N/64, M/128) = 512 = 2/CU.
#define STAGE_OUT(buf, k0) do {                                             \
    int c_ = tid;                                                           \
    int row_ = c_ >> 2, kc_ = c_ & 3;                                       \
    load_lds16(A + (size_t)(m0 + row_) * K + (k0) + kc_ * 8, &sA[buf][c_ * 8]); \
    load_lds16(W + (size_t)(n0 + row_) * K + (k0) + kc_ * 8, &sW[buf][c_ * 8]); \
    c_ = tid + 256; row_ = c_ >> 2; kc_ = c_ & 3;                           \
    load_lds16(A + (size_t)(m0 + row_) * K + (k0) + kc_ * 8, &sA[buf][c_ * 8]); \
  } while (0)

__global__ __launch_bounds__(256) void gemm_bt64_f16(
    const _Float16* __restrict__ A,   // [M,K]
    const _Float16* __restrict__ W,   // [N,K]
    const float*    __restrict__ bias,// [N]
    float*          __restrict__ Cf,  // [M,N]
    int M, int N, int K)
{
  __shared__ _Float16 sA[2][128 * 32];
  __shared__ _Float16 sW[2][64 * 32];
  const int tid = threadIdx.x;
  const int l = tid & 63;
  const int w = tid >> 6;
  const int wr = w >> 1, wc = w & 1;
  const int m0 = blockIdx.y * 128, n0 = blockIdx.x * 64;

  f32x4 acc[4][2] = {};

  STAGE_OUT(0, 0);
  __syncthreads();

  int cur = 0;
  for (int k0 = 0; k0 < K; k0 += 32) {
    if (k0 + 32 < K) STAGE_OUT(cur ^ 1, k0 + 32);

    half8 av[4], bv[2];
#pragma unroll
    for (int mi = 0; mi < 4; ++mi)
      av[mi] = *(const half8*)&sA[cur][(wr * 64 + mi * 16 + (l & 15)) * 32 + (l >> 4) * 8];
#pragma unroll
    for (int ni = 0; ni < 2; ++ni)
      bv[ni] = *(const half8*)&sW[cur][(wc * 32 + ni * 16 + (l & 15)) * 32 + (l >> 4) * 8];
#pragma unroll
    for (int mi = 0; mi < 4; ++mi)
#pragma unroll
      for (int ni = 0; ni < 2; ++ni)
        acc[mi][ni] = __builtin_amdgcn_mfma_f32_16x16x32_f16(av[mi], bv[ni], acc[mi][ni], 0, 0, 0);

    __syncthreads();
    cur ^= 1;
  }

#pragma unroll
  for (int mi = 0; mi < 4; ++mi) {
#pragma unroll
    for (int ni = 0; ni < 2; ++ni) {
      int row = m0 + wr * 64 + mi * 16 + ((l >> 4) << 2);
      int col = n0 + wc * 32 + ni * 16 + (l & 15);
      float bc = bias[col];
#pragma unroll
      for (int r = 0; r < 4; ++r)
        Cf[(size_t)(row + r) * N + col] = acc[mi][ni][r] + bc;
    }
  }
}

// ---------------- band-attention: rows i>=16, full-row attn writes ----------------
// grid: B*H*(S/32) blocks of 256 (4 waves); each wave handles 8 rows.
__global__ __launch_bounds__(256) void attn_band(
    const _Float16* __restrict__ Qh, const _Float16* __restrict__ Kh,
    const _Float16* __restrict__ Vh,
    float* __restrict__ attn, _Float16* __restrict__ ctx)
{
  __shared__ float Kb[96 * 65];
  __shared__ float Vb[96 * 65];
  __shared__ float Kg[16 * 65];
  __shared__ float Vg[16 * 65];
  __shared__ float qbuf[4][64];
  __shared__ float pbuf[4][128];

  const int bid = blockIdx.x;
  const int rb = bid & 63;
  const int h  = (bid >> 6) & 15;
  const int b  = bid >> 10;
  const int i0 = rb * 32;
  const int jb0 = max(i0 - 32, 0);
  const int jb1 = min(i0 + 63, S_LEN - 1);
  const int Wn = jb1 - jb0 + 1;     // <= 96
  const int tid = threadIdx.x;

  for (int s = tid; s < Wn * 16; s += 256) {
    int j = s >> 4, d4 = (s & 15) << 2;
    size_t base = ((size_t)b * S_LEN + jb0 + j) * D_MODEL + h * HEAD_D + d4;
    half4 kv = *(const half4*)(Kh + base);
    half4 vv = *(const half4*)(Vh + base);
    int o = j * 65 + d4;
    Kb[o] = (float)kv[0]; Kb[o+1] = (float)kv[1]; Kb[o+2] = (float)kv[2]; Kb[o+3] = (float)kv[3];
    Vb[o] = (float)vv[0]; Vb[o+1] = (float)vv[1]; Vb[o+2] = (float)vv[2]; Vb[o+3] = (float)vv[3];
  }
  {
    int s = tid;  // 16*16 = 256 slots exactly
    int j = s >> 4, d4 = (s & 15) << 2;
    size_t base = ((size_t)b * S_LEN + j) * D_MODEL + h * HEAD_D + d4;
    half4 kv = *(const half4*)(Kh + base);
    half4 vv = *(const half4*)(Vh + base);
    int o = j * 65 + d4;
    Kg[o] = (float)kv[0]; Kg[o+1] = (float)kv[1]; Kg[o+2] = (float)kv[2]; Kg[o+3] = (float)kv[3];
    Vg[o] = (float)vv[0]; Vg[o+1] = (float)vv[1]; Vg[o+2] = (float)vv[2]; Vg[o+3] = (float)vv[3];
  }
  __syncthreads();

  const int l = tid & 63, w = tid >> 6;
  for (int rr = 0; rr < 8; ++rr) {
    const int i = i0 + w * 8 + rr;
    if (i < NGLOB) continue;  // handled fully by attn_global

    qbuf[w][l] = (float)Qh[((size_t)b * S_LEN + i) * D_MODEL + h * HEAD_D + l];

    const int b0n = max(i - 32, 16);
    const int b1n = min(i + 32, S_LEN - 1);
    const int nj = 16 + (b1n - b0n + 1);   // <= 81

    const int  j1 = (l < 16) ? l : (b0n + l - 16);
    const bool v1 = l < nj;
    const int  jj2 = l + 64;
    const bool v2 = jj2 < nj;
    const int  j2 = v2 ? (b0n + jj2 - 16) : b0n;

    const float* kr1 = (l < 16) ? &Kg[l * 65] : &Kb[((v1 ? j1 : b0n) - jb0) * 65];
    const float* kr2 = &Kb[(j2 - jb0) * 65];

    float s1 = 0.f, s2 = 0.f;
#pragma unroll 8
    for (int d = 0; d < 64; ++d) {
      float qd = qbuf[w][d];
      s1 += qd * kr1[d];
      s2 += qd * kr2[d];
    }
    s1 *= 0.125f; s2 *= 0.125f;
    if (!v1) s1 = -1e30f;
    if (!v2) s2 = -1e30f;

    float mx = fmaxf(s1, s2);
#pragma unroll
    for (int o = 32; o; o >>= 1) mx = fmaxf(mx, __shfl_xor(mx, o));
    float e1 = v1 ? __expf(s1 - mx) : 0.f;
    float e2 = v2 ? __expf(s2 - mx) : 0.f;
    float sm = e1 + e2;
#pragma unroll
    for (int o = 32; o; o >>= 1) sm += __shfl_xor(sm, o);
    float inv = 1.f / sm;
    float p1 = e1 * inv, p2 = e2 * inv;

    pbuf[w][l] = p1;        // pbuf[jj]: jj<16 -> global col jj; else col b0n+jj-16
    pbuf[w][64 + l] = p2;

    // full-row attn write: 2048 floats = 8 x (64 lanes x float4), single pass
    float* arow = attn + ((size_t)(b * NH + h) * S_LEN + i) * S_LEN;
#pragma unroll
    for (int t = 0; t < 8; ++t) {
      const int lo = t * 256;
      const int j0 = lo + l * 4;
      f32x4 o4 = {0.f, 0.f, 0.f, 0.f};
      const bool hasAny = (lo < NGLOB) || !((b1n < lo) || (b0n >= lo + 256));
      if (hasAny) {
#pragma unroll
        for (int r = 0; r < 4; ++r) {
          int j = j0 + r;
          float v = 0.f;
          if (j < NGLOB) v = pbuf[w][j];
          else if (j >= b0n && j <= b1n) v = pbuf[w][16 + j - b0n];
          o4[r] = v;
        }
      }
      *(f32x4*)(arow + j0) = o4;
    }

    float c = 0.f;
    for (int jj = 0; jj < nj; ++jj) {
      float p = pbuf[w][jj];
      const float* vr = (jj < 16) ? &Vg[jj * 65] : &Vb[(b0n + jj - 16 - jb0) * 65];
      c += p * vr[l];
    }
    ctx[((size_t)b * S_LEN + i) * D_MODEL + h * HEAD_D + l] = (_Float16)c;
  }
}

// ---------------- global rows: i < 16, full 2048-wide softmax ----------------
__global__ __launch_bounds__(256) void attn_global(
    const _Float16* __restrict__ Qh, const _Float16* __restrict__ Kh,
    const _Float16* __restrict__ Vh,
    float* __restrict__ attn, _Float16* __restrict__ ctx)
{
  __shared__ float p[S_LEN];
  __shared__ float qbuf[64];
  __shared__ float red[8];
  __shared__ float part[4][64];

  const int bid = blockIdx.x;
  const int i = bid & 15;
  const int h = (bid >> 4) & 15;
  const int b = bid >> 8;
  const int tid = threadIdx.x;

  if (tid < 64) qbuf[tid] = (float)Qh[((size_t)b * S_LEN + i) * D_MODEL + h * HEAD_D + tid];
  __syncthreads();

  float lmax = -1e30f;
  for (int j = tid; j < S_LEN; j += 256) {
    const half8* kr = (const half8*)(Kh + ((size_t)b * S_LEN + j) * D_MODEL + h * HEAD_D);
    float s = 0.f;
#pragma unroll
    for (int c8 = 0; c8 < 8; ++c8) {
      half8 kv = kr[c8];
#pragma unroll
      for (int r = 0; r < 8; ++r) s += qbuf[c8 * 8 + r] * (float)kv[r];
    }
    s *= 0.125f;
    p[j] = s;
    lmax = fmaxf(lmax, s);
  }
#pragma unroll
  for (int o = 32; o; o >>= 1) lmax = fmaxf(lmax, __shfl_xor(lmax, o));
  if ((tid & 63) == 0) red[tid >> 6] = lmax;
  __syncthreads();
  const float mx = fmaxf(fmaxf(red[0], red[1]), fmaxf(red[2], red[3]));

  float lsum = 0.f;
  for (int j = tid; j < S_LEN; j += 256) {
    float e = __expf(p[j] - mx);
    p[j] = e;
    lsum += e;
  }
#pragma unroll
  for (int o = 32; o; o >>= 1) lsum += __shfl_xor(lsum, o);
  if ((tid & 63) == 0) red[4 + (tid >> 6)] = lsum;
  __syncthreads();
  const float inv = 1.f / (red[4] + red[5] + red[6] + red[7]);

  float* arow = attn + ((size_t)(b * NH + h) * S_LEN + i) * S_LEN;
  for (int j = tid; j < S_LEN; j += 256) {
    float pv = p[j] * inv;
    p[j] = pv;
    arow[j] = pv;
  }
  __syncthreads();

  const int d = tid & 63, c4 = tid >> 6;
  float c = 0.f;
  for (int j = c4 * 512; j < c4 * 512 + 512; ++j)
    c += p[j] * (float)Vh[((size_t)b * S_LEN + j) * D_MODEL + h * HEAD_D + d];
  part[c4][d] = c;
  __syncthreads();
  if (tid < 64) {
    float cc = part[0][tid] + part[1][tid] + part[2][tid] + part[3][tid];
    ctx[((size_t)b * S_LEN + i) * D_MODEL + h * HEAD_D + tid] = (_Float16)cc;
  }
}

// ---------------- launch ----------------
extern "C" void kernel_launch(void* const* d_in, const int* in_sizes, int n_in,
                              void* d_out, int out_size, void* d_ws, size_t ws_size,
                              hipStream_t stream) {
  const float* query = (const float*)d_in[0];
  const float* key   = (const float*)d_in[1];
  const float* value = (const float*)d_in[2];
  const float* Wq = (const float*)d_in[3];
  const float* bq = (const float*)d_in[4];
  const float* Wk = (const float*)d_in[5];
  const float* bk = (const float*)d_in[6];
  const float* Wv = (const float*)d_in[7];
  const float* bv = (const float*)d_in[8];
  const float* Wo = (const float*)d_in[9];
  const float* bo = (const float*)d_in[10];

  float* out  = (float*)d_out;
  float* attn = out + (size_t)BATCH * S_LEN * D_MODEL;

  const size_t XN = (size_t)BATCH * S_LEN * D_MODEL;  // 4,194,304
  const size_t WN = (size_t)D_MODEL * D_MODEL;        // 1,048,576
  _Float16* ws   = (_Float16*)d_ws;
  _Float16* X16q = ws;
  _Float16* X16k = X16q + XN;
  _Float16* X16v = X16k + XN;
  _Float16* W16q = X16v + XN;
  _Float16* W16k = W16q + WN;
  _Float16* W16v = W16k + WN;
  _Float16* W16o = W16v + WN;
  _Float16* Q16  = W16o + WN;
  _Float16* K16  = Q16 + XN;
  _Float16* V16  = K16 + XN;
  _Float16* C16  = V16 + XN;
  // total: 7*XN + 4*WN = 33,554,432 halfs = 64 MiB of ws

  const int M = BATCH * S_LEN;  // 4096

  // 1. batched converts (2 dispatches)
  dim3 gi(XN / 1024, 3);
  cvt_in3<<<gi, 256, 0, stream>>>(query, key, value, X16q, X16k, X16v, (int)XN);
  dim3 gw(WN / 1024, 4);
  cvt_w4<<<gw, 256, 0, stream>>>(Wq, Wk, Wv, Wo, W16q, W16k, W16v, W16o, (int)WN);

  // 2. batched Q/K/V projections: one dispatch, 768 blocks = 3/CU, 2-phase dbuf
  dim3 gp(D_MODEL / 128, M / 128, 3);  // 8 x 32 x 3
  gemm_qkv_f16<<<gp, 256, 0, stream>>>(X16q, X16k, X16v, W16q, W16k, W16v,
                                       bq, bk, bv, Q16, K16, V16, M, D_MODEL, D_MODEL);

  // 3. attention (attn matrix fully written here: band rows 16.., global rows 0..15)
  attn_band<<<BATCH * NH * (S_LEN / 32), 256, 0, stream>>>(Q16, K16, V16, attn, C16);
  attn_global<<<BATCH * NH * NGLOB, 256, 0, stream>>>(Q16, K16, V16, attn, C16);

  // 4. out = ctx @ Wo^T + bo  (128x64 tile -> 512 blocks = 2/CU, 2-phase dbuf)
  dim3 gf(D_MODEL / 64, M / 128);      // 16 x 32
  gemm_bt64_f16<<<gf, 256, 0, stream>>>(C16, W16o, bo, out, M, D_MODEL, D_MODEL);
}